// Round 4
// baseline (76.927 us; speedup 1.0000x reference)
//
#include <hip/hip_runtime.h>
#include <math.h>

// Problem constants (match reference)
#define B_  4
#define C_  128
#define H_  240
#define W_  320
#define N_  1024
#define NPTS (B_ * N_)          // 4096
#define HW_ (H_ * W_)
#define NBINS 960               // B_ * H_ / ... = 4*240 = 960 (key = b*240 + y0)

typedef float f4 __attribute__((ext_vector_type(4)));
typedef float f2 __attribute__((ext_vector_type(2)));

__device__ __forceinline__ f4 load4(const float* p) {
    f4 v; __builtin_memcpy(&v, p, 16); return v;
}
__device__ __forceinline__ f2 load2(const float* p) {
    f2 v; __builtin_memcpy(&v, p, 8); return v;
}

__device__ __forceinline__ float wave_reduce(float v) {
    #pragma unroll
    for (int off = 32; off > 0; off >>= 1)
        v += __shfl_xor(v, off, 64);
    return v;
}

// ---------------------------------------------------------------------------
// Kernel 0: counting-sort the 4096 points by (batch, y0) for DRAM row locality.
// Single block, 1024 threads. perm[pos] = original point id.
// (Within-bin order is atomic-races nondeterministic, but per-point results are
//  bitwise identical regardless of which wave computes them, and the final
//  reduction is fixed-order -> output deterministic.)
// ---------------------------------------------------------------------------
__global__ __launch_bounds__(1024) void gn_sort_kernel(
    const float* __restrict__ mb, const float* __restrict__ noise,
    int* __restrict__ perm)
{
    __shared__ int hist[NBINS];
    __shared__ int cursor[NBINS];
    for (int i = threadIdx.x; i < NBINS; i += 1024) hist[i] = 0;
    __syncthreads();

    int mykey[4];
    #pragma unroll
    for (int k = 0; k < 4; ++k) {
        const int p = threadIdx.x + (k << 10);
        const float uby = mb[p * 2 + 1] * 0.125f;
        const float ys  = 2.0f * noise[p * 2 + 1] - 1.0f + uby;
        const int y0 = min(max((int)floorf(ys), 1), H_ - 3);
        mykey[k] = (p >> 10) * H_ + y0;
        atomicAdd(&hist[mykey[k]], 1);
    }
    __syncthreads();

    // exclusive scan of 960 bins by wave 0 (15 bins/lane + shfl scan)
    if (threadIdx.x < 64) {
        const int lane = threadIdx.x;
        const int base = lane * 15;
        int loc[15];
        int s = 0;
        #pragma unroll
        for (int i = 0; i < 15; ++i) { loc[i] = s; s += hist[base + i]; }
        int incl = s;
        #pragma unroll
        for (int off = 1; off < 64; off <<= 1) {
            const int v = __shfl_up(incl, off, 64);
            if (lane >= off) incl += v;
        }
        const int excl = incl - s;
        #pragma unroll
        for (int i = 0; i < 15; ++i) cursor[base + i] = excl + loc[i];
    }
    __syncthreads();

    #pragma unroll
    for (int k = 0; k < 4; ++k) {
        const int p = threadIdx.x + (k << 10);
        const int pos = atomicAdd(&cursor[mykey[k]], 1);
        perm[pos] = p;
    }
}

// ---------------------------------------------------------------------------
// Kernel 1: gather + per-point GN math. TWO waves per point (1 channel/lane),
// 256-thread blocks = 2 points/block, 8192 waves total (32/CU).
// ---------------------------------------------------------------------------
__global__ __launch_bounds__(256) void gn_point_kernel(
    const float* __restrict__ Fa, const float* __restrict__ Fb,
    const float* __restrict__ ma, const float* __restrict__ mb,
    const float* __restrict__ noise, const int* __restrict__ perm,
    float* __restrict__ ws_e1, float* __restrict__ ws_ld)
{
    const int wid  = threadIdx.x >> 6;            // 0..3
    const int lane = threadIdx.x & 63;
    const int slot = (blockIdx.x << 1) | (wid >> 1);
    const int p = perm[slot];                     // sorted point id
    const int b = p >> 10;
    const int c = ((wid & 1) << 6) | lane;        // channel 0..127

    const float inv_level = 0.125f;
    const float xa  = ma[p * 2 + 0] * inv_level;
    const float ya  = ma[p * 2 + 1] * inv_level;
    const float ubx = mb[p * 2 + 0] * inv_level;
    const float uby = mb[p * 2 + 1] * inv_level;
    const float xs  = 2.0f * noise[p * 2 + 0] - 1.0f + ubx;
    const float ys  = 2.0f * noise[p * 2 + 1] - 1.0f + uby;

    // ---- F_a bilinear indices ----
    const float ax0f = floorf(xa), ay0f = floorf(ya);
    const float awx = xa - ax0f, awy = ya - ay0f;
    const int ax0 = min(max((int)ax0f, 0), W_ - 2);
    const int ay0 = min(max((int)ay0f, 0), H_ - 2);

    // ---- F_b patch indices (interior guaranteed) ----
    const float bx0f = floorf(xs), by0f = floorf(ys);
    const float wx = xs - bx0f, wy = ys - by0f;
    const int x0 = min(max((int)bx0f, 1), W_ - 3);
    const int y0 = min(max((int)by0f, 1), H_ - 3);
    const int xm = x0 - 1;

    const int o_y0 = y0 * W_ + xm;                // 4 floats
    const int o_y1 = (y0 + 1) * W_ + xm;          // 4 floats
    const int o_ym = (y0 - 1) * W_ + x0;          // 2 floats
    const int o_yp = (y0 + 2) * W_ + x0;          // 2 floats
    const int o_a0 = ay0 * W_ + ax0;              // 2 floats
    const int o_a1 = (ay0 + 1) * W_ + ax0;        // 2 floats

    const size_t plane = ((size_t)b * C_ + c) * HW_;
    const float* __restrict__ fa = Fa + plane;
    const float* __restrict__ fb = Fb + plane;

    // ---------- 6 independent vector gathers ----------
    const f4 row0 = load4(fb + o_y0);
    const f4 row1 = load4(fb + o_y1);
    const f2 rm   = load2(fb + o_ym);
    const f2 rp   = load2(fb + o_yp);
    const f2 a0   = load2(fa + o_a0);
    const f2 a1   = load2(fa + o_a1);

    // ---------- weights ----------
    const float aw00 = (1.f - awx) * (1.f - awy);
    const float aw01 = awx * (1.f - awy);
    const float aw10 = (1.f - awx) * awy;
    const float aw11 = awx * awy;
    const float w00 = (1.f - wx) * (1.f - wy);
    const float w01 = wx * (1.f - wy);
    const float w10 = (1.f - wx) * wy;
    const float w11 = wx * wy;

    const float ft = a0.x * aw00 + a0.y * aw01 + a1.x * aw10 + a1.y * aw11;
    const float fs = row0.y * w00 + row0.z * w01 + row1.y * w10 + row1.z * w11;
    const float jx = 0.5f * ((row0.z - row0.x) * w00 + (row0.w - row0.y) * w01
                           + (row1.z - row1.x) * w10 + (row1.w - row1.y) * w11);
    const float jy = 0.5f * ((row1.y - rm.x) * w00 + (row1.z - rm.y) * w01
                           + (rp.x - row0.y) * w10 + (rp.y - row0.z) * w11);

    float vals[9];
    vals[0] = ft * ft;
    vals[1] = fs * fs;
    vals[2] = jx * fs;
    vals[3] = jx * ft;
    vals[4] = jy * fs;
    vals[5] = jy * ft;
    vals[6] = jx * jx;
    vals[7] = jx * jy;
    vals[8] = jy * jy;

    #pragma unroll
    for (int k = 0; k < 9; ++k)
        vals[k] = wave_reduce(vals[k]);

    __shared__ float sm[4][9];
    if (lane == 0) {
        #pragma unroll
        for (int k = 0; k < 9; ++k) sm[wid][k] = vals[k];
    }
    __syncthreads();

    // threads 0 (point slot 0) and 128 (point slot 1) finalize; each has its
    // own point's scalars in registers.
    if ((threadIdx.x & 127) == 0) {
        float s[9];
        #pragma unroll
        for (int k = 0; k < 9; ++k) s[k] = sm[wid][k] + sm[wid + 1][k];

        const float nt = fmaxf(sqrtf(s[0]), 1e-12f);
        const float ns = fmaxf(sqrtf(s[1]), 1e-12f);
        const float b0 = s[2] / ns - s[3] / nt;
        const float b1 = s[4] / ns - s[5] / nt;
        const float H00 = s[6] + 1e-9f;
        const float H01 = s[7];
        const float H11 = s[8] + 1e-9f;
        const float det = H00 * H11 - H01 * H01;
        const float inv = 1.0f / det;
        const float u0 = (H11 * b0 - H01 * b1) * inv;   // (Hinv @ b)[0]
        const float u1 = (H00 * b1 - H01 * b0) * inv;   // (Hinv @ b)[1]
        const float d0 = (ubx - xs) + u0;               // diff = ub - miu
        const float d1 = (uby - ys) + u1;
        const float quad = d0 * (H00 * d0 + H01 * d1) + d1 * (H01 * d0 + H11 * d1);
        ws_e1[p] = 0.5f * quad;
        ws_ld[p] = logf(det);
    }
}

// ---------------------------------------------------------------------------
// Kernel 2: single-block deterministic reduction of the 4096 partials.
// ---------------------------------------------------------------------------
__global__ __launch_bounds__(256) void gn_reduce_kernel(
    const float* __restrict__ ws_e1, const float* __restrict__ ws_ld,
    float* __restrict__ out)
{
    __shared__ double sm1[256];
    __shared__ double sm2[256];
    double a1 = 0.0, a2 = 0.0;
    for (int i = threadIdx.x; i < NPTS; i += 256) {
        a1 += (double)ws_e1[i];
        a2 += (double)ws_ld[i];
    }
    sm1[threadIdx.x] = a1;
    sm2[threadIdx.x] = a2;
    __syncthreads();
    for (int s = 128; s > 0; s >>= 1) {
        if (threadIdx.x < s) {
            sm1[threadIdx.x] += sm1[threadIdx.x + s];
            sm2[threadIdx.x] += sm2[threadIdx.x + s];
        }
        __syncthreads();
    }
    if (threadIdx.x == 0) {
        const double e1 = sm1[0];
        const double sum_ld = sm2[0];
        const double log2pi = (double)logf(6.283185307179586f);
        const double e2 = (double)NPTS * log2pi - 0.5 * sum_ld;
        const double e = 1.0 * e1 + (2.0 / 7.0) * e2;   // E1_LAMDA=1, E2_LAMDA=2/7
        out[0] = (float)(0.3 * e);                      // GN_LAMDA * e
        out[1] = (float)e1;
        out[2] = (float)e2;
    }
}

extern "C" void kernel_launch(void* const* d_in, const int* in_sizes, int n_in,
                              void* d_out, int out_size, void* d_ws, size_t ws_size,
                              hipStream_t stream) {
    const float* Fa    = (const float*)d_in[0];
    const float* Fb    = (const float*)d_in[1];
    const float* ma    = (const float*)d_in[2];
    const float* mb    = (const float*)d_in[3];
    const float* noise = (const float*)d_in[4];
    float* out = (float*)d_out;

    float* ws_e1 = (float*)d_ws;            // 4096 floats
    float* ws_ld = ws_e1 + NPTS;            // 4096 floats
    int*   perm  = (int*)(ws_ld + NPTS);    // 4096 ints   (48 KiB total)

    gn_sort_kernel<<<1, 1024, 0, stream>>>(mb, noise, perm);
    gn_point_kernel<<<NPTS / 2, 256, 0, stream>>>(Fa, Fb, ma, mb, noise, perm,
                                                  ws_e1, ws_ld);
    gn_reduce_kernel<<<1, 256, 0, stream>>>(ws_e1, ws_ld, out);
}

// Round 5
// 74.518 us; speedup vs baseline: 1.0323x; 1.0323x over previous
//
#include <hip/hip_runtime.h>
#include <math.h>

// Problem constants (match reference)
#define B_  4
#define C_  128
#define H_  240
#define W_  320
#define N_  1024
#define NPTS (B_ * N_)          // 4096
#define HW_ (H_ * W_)
#define NBINS 960               // key = b*240 + y0

typedef float f4 __attribute__((ext_vector_type(4)));
typedef float f2 __attribute__((ext_vector_type(2)));

__device__ __forceinline__ f4 load4(const float* p) {
    f4 v; __builtin_memcpy(&v, p, 16); return v;
}
__device__ __forceinline__ f2 load2(const float* p) {
    f2 v; __builtin_memcpy(&v, p, 8); return v;
}
__device__ __forceinline__ void store2(float* p, f2 v) {
    __builtin_memcpy(p, &v, 8);
}

// ---------------------------------------------------------------------------
// Kernel 0: two counting-sorts of the 4096 points:
//   permB: by (batch, y0 of F_b sample coord)   -> for the F_b gather pass
//   permA: by (batch, y0 of F_a sample coord)   -> for the F_a gather pass
// Within-bin placement is atomic-race nondeterministic, but every per-point
// value downstream is a pure function of the point id (no cross-lane math),
// so the final output is bitwise deterministic.
// ---------------------------------------------------------------------------
__global__ __launch_bounds__(1024) void gn_sort_kernel(
    const float* __restrict__ ma, const float* __restrict__ mb,
    const float* __restrict__ noise,
    int* __restrict__ permA, int* __restrict__ permB)
{
    __shared__ int hist[NBINS];
    __shared__ int cursor[NBINS];

    // ---- pass 1: key by F_b sample row ----
    for (int i = threadIdx.x; i < NBINS; i += 1024) hist[i] = 0;
    __syncthreads();
    int keyB[4];
    #pragma unroll
    for (int k = 0; k < 4; ++k) {
        const int p = threadIdx.x + (k << 10);
        const float ys = 2.0f * noise[p * 2 + 1] - 1.0f + mb[p * 2 + 1] * 0.125f;
        const int y0 = min(max((int)floorf(ys), 1), H_ - 3);
        keyB[k] = (p >> 10) * H_ + y0;
        atomicAdd(&hist[keyB[k]], 1);
    }
    __syncthreads();
    if (threadIdx.x < 64) {
        const int lane = threadIdx.x;
        const int base = lane * 15;
        int loc[15]; int s = 0;
        #pragma unroll
        for (int i = 0; i < 15; ++i) { loc[i] = s; s += hist[base + i]; }
        int incl = s;
        #pragma unroll
        for (int off = 1; off < 64; off <<= 1) {
            const int v = __shfl_up(incl, off, 64);
            if (lane >= off) incl += v;
        }
        const int excl = incl - s;
        #pragma unroll
        for (int i = 0; i < 15; ++i) cursor[base + i] = excl + loc[i];
    }
    __syncthreads();
    #pragma unroll
    for (int k = 0; k < 4; ++k) {
        const int p = threadIdx.x + (k << 10);
        permB[atomicAdd(&cursor[keyB[k]], 1)] = p;
    }
    __syncthreads();

    // ---- pass 2: key by F_a sample row ----
    for (int i = threadIdx.x; i < NBINS; i += 1024) hist[i] = 0;
    __syncthreads();
    int keyA[4];
    #pragma unroll
    for (int k = 0; k < 4; ++k) {
        const int p = threadIdx.x + (k << 10);
        const float ya = ma[p * 2 + 1] * 0.125f;
        const int y0 = min(max((int)floorf(ya), 0), H_ - 2);
        keyA[k] = (p >> 10) * H_ + y0;
        atomicAdd(&hist[keyA[k]], 1);
    }
    __syncthreads();
    if (threadIdx.x < 64) {
        const int lane = threadIdx.x;
        const int base = lane * 15;
        int loc[15]; int s = 0;
        #pragma unroll
        for (int i = 0; i < 15; ++i) { loc[i] = s; s += hist[base + i]; }
        int incl = s;
        #pragma unroll
        for (int off = 1; off < 64; off <<= 1) {
            const int v = __shfl_up(incl, off, 64);
            if (lane >= off) incl += v;
        }
        const int excl = incl - s;
        #pragma unroll
        for (int i = 0; i < 15; ++i) cursor[base + i] = excl + loc[i];
    }
    __syncthreads();
    #pragma unroll
    for (int k = 0; k < 4; ++k) {
        const int p = threadIdx.x + (k << 10);
        permA[atomicAdd(&cursor[keyA[k]], 1)] = p;
    }
}

// ---------------------------------------------------------------------------
// Kernel A: F_a gather. wave = (point-group, 2 channels); lane = point.
// 64 lanes of a wave hit ONE channel plane in a ~15-row window -> DRAM row hits.
// ws_ft[p*128 + c] = bilinear F_a sample (f2 store for the channel pair).
// ---------------------------------------------------------------------------
__global__ __launch_bounds__(256) void gn_ft_kernel(
    const float* __restrict__ Fa, const float* __restrict__ ma,
    const int* __restrict__ permA, float* __restrict__ ws_ft)
{
    const int w    = (blockIdx.x << 2) | (threadIdx.x >> 6);  // wave 0..4095
    const int lane = threadIdx.x & 63;
    const int pg   = w >> 6;                  // point group 0..63
    const int c0   = (w & 63) << 1;           // channels c0, c0+1
    const int p    = permA[(pg << 6) | lane];
    const int b    = p >> 10;

    const float xa = ma[p * 2 + 0] * 0.125f;
    const float ya = ma[p * 2 + 1] * 0.125f;
    const float ax0f = floorf(xa), ay0f = floorf(ya);
    const float awx = xa - ax0f, awy = ya - ay0f;
    const int ax0 = min(max((int)ax0f, 0), W_ - 2);
    const int ay0 = min(max((int)ay0f, 0), H_ - 2);
    const int o0 = ay0 * W_ + ax0;
    const int o1 = o0 + W_;

    const float* __restrict__ fa0 = Fa + ((size_t)(b * C_ + c0)) * HW_;
    const float* __restrict__ fa1 = fa0 + HW_;

    const f2 a0_0 = load2(fa0 + o0);
    const f2 a1_0 = load2(fa0 + o1);
    const f2 a0_1 = load2(fa1 + o0);
    const f2 a1_1 = load2(fa1 + o1);

    const float w00 = (1.f - awx) * (1.f - awy);
    const float w01 = awx * (1.f - awy);
    const float w10 = (1.f - awx) * awy;
    const float w11 = awx * awy;

    f2 ft;
    ft.x = a0_0.x * w00 + a0_0.y * w01 + a1_0.x * w10 + a1_0.y * w11;
    ft.y = a0_1.x * w00 + a0_1.y * w01 + a1_1.x * w10 + a1_1.y * w11;
    store2(ws_ft + (size_t)p * C_ + c0, ft);
}

// ---------------------------------------------------------------------------
// Kernel B: F_b gather. wave = (point-group, 2 channels); lane = point.
// Stores per-channel fs, jx, jy to planes [c*3+j][p].
// ---------------------------------------------------------------------------
__global__ __launch_bounds__(256) void gn_fb_kernel(
    const float* __restrict__ Fb, const float* __restrict__ mb,
    const float* __restrict__ noise, const int* __restrict__ permB,
    float* __restrict__ fjp)
{
    const int w    = (blockIdx.x << 2) | (threadIdx.x >> 6);
    const int lane = threadIdx.x & 63;
    const int pg   = w >> 6;
    const int c0   = (w & 63) << 1;
    const int p    = permB[(pg << 6) | lane];
    const int b    = p >> 10;

    const float ubx = mb[p * 2 + 0] * 0.125f;
    const float uby = mb[p * 2 + 1] * 0.125f;
    const float xs  = 2.0f * noise[p * 2 + 0] - 1.0f + ubx;
    const float ys  = 2.0f * noise[p * 2 + 1] - 1.0f + uby;

    const float bx0f = floorf(xs), by0f = floorf(ys);
    const float wx = xs - bx0f, wy = ys - by0f;
    const int x0 = min(max((int)bx0f, 1), W_ - 3);
    const int y0 = min(max((int)by0f, 1), H_ - 3);

    const int o_y0 = y0 * W_ + (x0 - 1);       // 4 floats
    const int o_y1 = o_y0 + W_;                // 4 floats
    const int o_ym = (y0 - 1) * W_ + x0;       // 2 floats
    const int o_yp = (y0 + 2) * W_ + x0;       // 2 floats

    const float* __restrict__ fb0 = Fb + ((size_t)(b * C_ + c0)) * HW_;
    const float* __restrict__ fb1 = fb0 + HW_;

    const f4 r0_0 = load4(fb0 + o_y0);
    const f4 r1_0 = load4(fb0 + o_y1);
    const f2 rm_0 = load2(fb0 + o_ym);
    const f2 rp_0 = load2(fb0 + o_yp);
    const f4 r0_1 = load4(fb1 + o_y0);
    const f4 r1_1 = load4(fb1 + o_y1);
    const f2 rm_1 = load2(fb1 + o_ym);
    const f2 rp_1 = load2(fb1 + o_yp);

    const float w00 = (1.f - wx) * (1.f - wy);
    const float w01 = wx * (1.f - wy);
    const float w10 = (1.f - wx) * wy;
    const float w11 = wx * wy;

    #pragma unroll
    for (int ch = 0; ch < 2; ++ch) {
        const f4 row0 = ch ? r0_1 : r0_0;
        const f4 row1 = ch ? r1_1 : r1_0;
        const f2 rm   = ch ? rm_1 : rm_0;
        const f2 rp   = ch ? rp_1 : rp_0;
        const float fs = row0.y * w00 + row0.z * w01 + row1.y * w10 + row1.z * w11;
        const float jx = 0.5f * ((row0.z - row0.x) * w00 + (row0.w - row0.y) * w01
                               + (row1.z - row1.x) * w10 + (row1.w - row1.y) * w11);
        const float jy = 0.5f * ((row1.y - rm.x) * w00 + (row1.z - rm.y) * w01
                               + (rp.x - row0.y) * w10 + (rp.y - row0.z) * w11);
        const size_t base = (size_t)(c0 + ch) * 3 * NPTS + p;
        fjp[base]            = fs;
        fjp[base + NPTS]     = jx;
        fjp[base + 2 * NPTS] = jy;
    }
}

// ---------------------------------------------------------------------------
// Kernel C: per-point channel reduction (fixed order c=0..127) + 2x2 GN solve.
// thread = point id. Deterministic.
// ---------------------------------------------------------------------------
__global__ __launch_bounds__(256) void gn_combine_kernel(
    const float* __restrict__ ws_ft, const float* __restrict__ fjp,
    const float* __restrict__ mb, const float* __restrict__ noise,
    float* __restrict__ ws_e1, float* __restrict__ ws_ld)
{
    const int p = blockIdx.x * 256 + threadIdx.x;

    float s[9];
    #pragma unroll
    for (int k = 0; k < 9; ++k) s[k] = 0.f;

    const float* ftp = ws_ft + (size_t)p * C_;
    #pragma unroll 4
    for (int c = 0; c < C_; ++c) {
        const float ft = ftp[c];
        const size_t base = (size_t)c * 3 * NPTS + p;
        const float fs = fjp[base];
        const float jx = fjp[base + NPTS];
        const float jy = fjp[base + 2 * NPTS];
        s[0] += ft * ft;
        s[1] += fs * fs;
        s[2] += jx * fs;
        s[3] += jx * ft;
        s[4] += jy * fs;
        s[5] += jy * ft;
        s[6] += jx * jx;
        s[7] += jx * jy;
        s[8] += jy * jy;
    }

    const float ubx = mb[p * 2 + 0] * 0.125f;
    const float uby = mb[p * 2 + 1] * 0.125f;
    const float xs  = 2.0f * noise[p * 2 + 0] - 1.0f + ubx;
    const float ys  = 2.0f * noise[p * 2 + 1] - 1.0f + uby;

    const float nt = fmaxf(sqrtf(s[0]), 1e-12f);
    const float ns = fmaxf(sqrtf(s[1]), 1e-12f);
    const float b0 = s[2] / ns - s[3] / nt;
    const float b1 = s[4] / ns - s[5] / nt;
    const float H00 = s[6] + 1e-9f;
    const float H01 = s[7];
    const float H11 = s[8] + 1e-9f;
    const float det = H00 * H11 - H01 * H01;
    const float inv = 1.0f / det;
    const float u0 = (H11 * b0 - H01 * b1) * inv;
    const float u1 = (H00 * b1 - H01 * b0) * inv;
    const float d0 = (ubx - xs) + u0;
    const float d1 = (uby - ys) + u1;
    const float quad = d0 * (H00 * d0 + H01 * d1) + d1 * (H01 * d0 + H11 * d1);
    ws_e1[p] = 0.5f * quad;
    ws_ld[p] = logf(det);
}

// ---------------------------------------------------------------------------
// Kernel D: single-block deterministic reduction of the 4096 partials.
// ---------------------------------------------------------------------------
__global__ __launch_bounds__(256) void gn_reduce_kernel(
    const float* __restrict__ ws_e1, const float* __restrict__ ws_ld,
    float* __restrict__ out)
{
    __shared__ double sm1[256];
    __shared__ double sm2[256];
    double a1 = 0.0, a2 = 0.0;
    for (int i = threadIdx.x; i < NPTS; i += 256) {
        a1 += (double)ws_e1[i];
        a2 += (double)ws_ld[i];
    }
    sm1[threadIdx.x] = a1;
    sm2[threadIdx.x] = a2;
    __syncthreads();
    for (int s = 128; s > 0; s >>= 1) {
        if (threadIdx.x < s) {
            sm1[threadIdx.x] += sm1[threadIdx.x + s];
            sm2[threadIdx.x] += sm2[threadIdx.x + s];
        }
        __syncthreads();
    }
    if (threadIdx.x == 0) {
        const double e1 = sm1[0];
        const double sum_ld = sm2[0];
        const double log2pi = (double)logf(6.283185307179586f);
        const double e2 = (double)NPTS * log2pi - 0.5 * sum_ld;
        const double e = 1.0 * e1 + (2.0 / 7.0) * e2;   // E1_LAMDA=1, E2_LAMDA=2/7
        out[0] = (float)(0.3 * e);                      // GN_LAMDA * e
        out[1] = (float)e1;
        out[2] = (float)e2;
    }
}

extern "C" void kernel_launch(void* const* d_in, const int* in_sizes, int n_in,
                              void* d_out, int out_size, void* d_ws, size_t ws_size,
                              hipStream_t stream) {
    const float* Fa    = (const float*)d_in[0];
    const float* Fb    = (const float*)d_in[1];
    const float* ma    = (const float*)d_in[2];
    const float* mb    = (const float*)d_in[3];
    const float* noise = (const float*)d_in[4];
    float* out = (float*)d_out;

    float* ws_e1 = (float*)d_ws;                    // 4096
    float* ws_ld = ws_e1 + NPTS;                    // 4096
    int*   permA = (int*)(ws_ld + NPTS);            // 4096
    int*   permB = permA + NPTS;                    // 4096
    float* ws_ft = (float*)(permB + NPTS);          // 4096*128   (2 MiB)
    float* fjp   = ws_ft + (size_t)NPTS * C_;       // 128*3*4096 (6 MiB)

    gn_sort_kernel<<<1, 1024, 0, stream>>>(ma, mb, noise, permA, permB);
    gn_ft_kernel<<<1024, 256, 0, stream>>>(Fa, ma, permA, ws_ft);
    gn_fb_kernel<<<1024, 256, 0, stream>>>(Fb, mb, noise, permB, fjp);
    gn_combine_kernel<<<NPTS / 256, 256, 0, stream>>>(ws_ft, fjp, mb, noise,
                                                      ws_e1, ws_ld);
    gn_reduce_kernel<<<1, 256, 0, stream>>>(ws_e1, ws_ld, out);
}